// Round 2
// baseline (590.492 us; speedup 1.0000x reference)
//
#include <hip/hip_runtime.h>
#include <hip/hip_bf16.h>
#include <math.h>

typedef __bf16 bf16;
typedef float f32x4 __attribute__((ext_vector_type(4)));
typedef bf16 bf16x8 __attribute__((ext_vector_type(8)));

#define MFMA16(a, b, c) __builtin_amdgcn_mfma_f32_16x16x32_bf16(a, b, c, 0, 0, 0)

// Problem constants
static constexpr int T_SEQ = 2048;
static constexpr int CDIM  = 1024;
static constexpr int NH    = 16;
static constexpr int DH    = 64;
// log2(10000)/64
static constexpr float FREQ_C = 0.20762050593045998f;

// ---------------------------------------------------------------------------
// fp32 -> bf16 conversion (inputs are float32 per the reference; all compute
// kernels consume bf16 from workspace). 8 elems/thread, 32B in / 16B out.
// ---------------------------------------------------------------------------
__global__ __launch_bounds__(256)
void cvt_f32_bf16(const float* __restrict__ in, bf16* __restrict__ out, int n8) {
    const int i = blockIdx.x * 256 + threadIdx.x;
    if (i >= n8) return;
    const f32x4* p = (const f32x4*)(in + (size_t)i * 8);
    const f32x4 lo = p[0], hi = p[1];
    bf16x8 o;
    o[0] = (bf16)lo[0]; o[1] = (bf16)lo[1]; o[2] = (bf16)lo[2]; o[3] = (bf16)lo[3];
    o[4] = (bf16)hi[0]; o[5] = (bf16)hi[1]; o[6] = (bf16)hi[2]; o[7] = (bf16)hi[3];
    *(bf16x8*)(out + (size_t)i * 8) = o;
}

// ---------------------------------------------------------------------------
// GEMM: C[m][n] = sum_k X[m][k] * W[n][k]   (both K-major, bf16, fp32 acc)
// 64x64 tile per 256-thread WG (4 waves in 2x2), BK=64.
// QKV variant: fused interleaved-RoPE + 1/sqrt(D) scale on Q, scatter to
// (B,H,T,D) layouts for Q,K,V.
// ---------------------------------------------------------------------------
__global__ __launch_bounds__(256)
void gemm_qkv(const bf16* __restrict__ X, const bf16* __restrict__ W,
              bf16* __restrict__ Qo, bf16* __restrict__ Ko, bf16* __restrict__ Vo) {
    __shared__ __align__(16) bf16 ash[64][72];   // +8 pad: 2-way bank alias (free)
    __shared__ __align__(16) bf16 bsh[64][72];
    const int tid  = threadIdx.x;
    const int lane = tid & 63;
    const int wave = tid >> 6;
    const int quad = lane >> 4;
    const int l16  = lane & 15;
    const int wm   = wave >> 1, wn = wave & 1;
    const int bm   = blockIdx.y, bn = blockIdx.x;
    const int lr   = tid >> 3;            // 0..31
    const int lc   = (tid & 7) * 8;       // 0,8,...,56

    const bf16* Xg = X + (size_t)(bm * 64) * CDIM;
    const bf16* Wg = W + (size_t)(bn * 64) * CDIM;

    f32x4 acc[2][2];
    const f32x4 zero4 = {0.f, 0.f, 0.f, 0.f};
    acc[0][0] = zero4; acc[0][1] = zero4; acc[1][0] = zero4; acc[1][1] = zero4;

    for (int kk = 0; kk < CDIM; kk += 64) {
        bf16x8 a0 = *(const bf16x8*)(Xg + (size_t)lr * CDIM + kk + lc);
        bf16x8 a1 = *(const bf16x8*)(Xg + (size_t)(lr + 32) * CDIM + kk + lc);
        bf16x8 b0 = *(const bf16x8*)(Wg + (size_t)lr * CDIM + kk + lc);
        bf16x8 b1 = *(const bf16x8*)(Wg + (size_t)(lr + 32) * CDIM + kk + lc);
        __syncthreads();   // previous iteration's LDS reads complete
        *(bf16x8*)&ash[lr][lc]      = a0;
        *(bf16x8*)&ash[lr + 32][lc] = a1;
        *(bf16x8*)&bsh[lr][lc]      = b0;
        *(bf16x8*)&bsh[lr + 32][lc] = b1;
        __syncthreads();
#pragma unroll
        for (int ks = 0; ks < 2; ks++) {
            bf16x8 af0 = *(const bf16x8*)&ash[wm * 32 + l16][ks * 32 + quad * 8];
            bf16x8 af1 = *(const bf16x8*)&ash[wm * 32 + 16 + l16][ks * 32 + quad * 8];
            bf16x8 bf0 = *(const bf16x8*)&bsh[wn * 32 + l16][ks * 32 + quad * 8];
            bf16x8 bf1 = *(const bf16x8*)&bsh[wn * 32 + 16 + l16][ks * 32 + quad * 8];
            acc[0][0] = MFMA16(af0, bf0, acc[0][0]);
            acc[0][1] = MFMA16(af0, bf1, acc[0][1]);
            acc[1][0] = MFMA16(af1, bf0, acc[1][0]);
            acc[1][1] = MFMA16(af1, bf1, acc[1][1]);
        }
    }

    // Epilogue: C-layout row = quad*4+r, col = l16. RoPE pair partner is lane^1.
#pragma unroll
    for (int tm = 0; tm < 2; tm++) {
#pragma unroll
        for (int tn = 0; tn < 2; tn++) {
            const int n  = bn * 64 + wn * 32 + tn * 16 + l16;
            const int rr = n >> 10;            // 0=q 1=k 2=v
            const int h  = (n >> 6) & 15;
            const int d  = n & 63;
#pragma unroll
            for (int r = 0; r < 4; r++) {
                const int m = bm * 64 + wm * 32 + tm * 16 + quad * 4 + r;
                const int b = m >> 11;
                const int t = m & (T_SEQ - 1);
                float val = acc[tm][tn][r];
                float partner = __shfl_xor(val, 1);   // neighboring d (pair element)
                const size_t dst = ((size_t)(b * NH + h) * T_SEQ + t) * DH + d;
                if (rr == 2) {
                    Vo[dst] = (bf16)val;
                } else {
                    const float inv = exp2f(-(float)(d & ~1) * FREQ_C);
                    const float ang = (float)t * inv;
                    const float c = cosf(ang), s = sinf(ang);
                    float o;
                    if (d & 1) o = partner * s + val * c;   // odd slot: e*sin + o*cos
                    else       o = val * c - partner * s;   // even slot: e*cos - o*sin
                    if (rr == 0) { o *= 0.125f; Qo[dst] = (bf16)o; }  // fold 1/sqrt(64)
                    else         { Ko[dst] = (bf16)o; }
                }
            }
        }
    }
}

// ---------------------------------------------------------------------------
// Plain GEMM for out-projection: out[m][n] = sum_k Y[m][k] * W[n][k]
// Output is fp32 (reference output dtype).
// ---------------------------------------------------------------------------
__global__ __launch_bounds__(256)
void gemm_proj(const bf16* __restrict__ X, const bf16* __restrict__ W,
               float* __restrict__ Out) {
    __shared__ __align__(16) bf16 ash[64][72];
    __shared__ __align__(16) bf16 bsh[64][72];
    const int tid  = threadIdx.x;
    const int lane = tid & 63;
    const int wave = tid >> 6;
    const int quad = lane >> 4;
    const int l16  = lane & 15;
    const int wm   = wave >> 1, wn = wave & 1;
    const int bm   = blockIdx.y, bn = blockIdx.x;
    const int lr   = tid >> 3;
    const int lc   = (tid & 7) * 8;

    const bf16* Xg = X + (size_t)(bm * 64) * CDIM;
    const bf16* Wg = W + (size_t)(bn * 64) * CDIM;

    f32x4 acc[2][2];
    const f32x4 zero4 = {0.f, 0.f, 0.f, 0.f};
    acc[0][0] = zero4; acc[0][1] = zero4; acc[1][0] = zero4; acc[1][1] = zero4;

    for (int kk = 0; kk < CDIM; kk += 64) {
        bf16x8 a0 = *(const bf16x8*)(Xg + (size_t)lr * CDIM + kk + lc);
        bf16x8 a1 = *(const bf16x8*)(Xg + (size_t)(lr + 32) * CDIM + kk + lc);
        bf16x8 b0 = *(const bf16x8*)(Wg + (size_t)lr * CDIM + kk + lc);
        bf16x8 b1 = *(const bf16x8*)(Wg + (size_t)(lr + 32) * CDIM + kk + lc);
        __syncthreads();
        *(bf16x8*)&ash[lr][lc]      = a0;
        *(bf16x8*)&ash[lr + 32][lc] = a1;
        *(bf16x8*)&bsh[lr][lc]      = b0;
        *(bf16x8*)&bsh[lr + 32][lc] = b1;
        __syncthreads();
#pragma unroll
        for (int ks = 0; ks < 2; ks++) {
            bf16x8 af0 = *(const bf16x8*)&ash[wm * 32 + l16][ks * 32 + quad * 8];
            bf16x8 af1 = *(const bf16x8*)&ash[wm * 32 + 16 + l16][ks * 32 + quad * 8];
            bf16x8 bf0 = *(const bf16x8*)&bsh[wn * 32 + l16][ks * 32 + quad * 8];
            bf16x8 bf1 = *(const bf16x8*)&bsh[wn * 32 + 16 + l16][ks * 32 + quad * 8];
            acc[0][0] = MFMA16(af0, bf0, acc[0][0]);
            acc[0][1] = MFMA16(af0, bf1, acc[0][1]);
            acc[1][0] = MFMA16(af1, bf0, acc[1][0]);
            acc[1][1] = MFMA16(af1, bf1, acc[1][1]);
        }
    }

#pragma unroll
    for (int tm = 0; tm < 2; tm++) {
#pragma unroll
        for (int tn = 0; tn < 2; tn++) {
            const int n = bn * 64 + wn * 32 + tn * 16 + l16;
#pragma unroll
            for (int r = 0; r < 4; r++) {
                const int m = bm * 64 + wm * 32 + tm * 16 + quad * 4 + r;
                Out[(size_t)m * CDIM + n] = acc[tm][tn][r];
            }
        }
    }
}

// ---------------------------------------------------------------------------
// Flash attention: one WG = one (b,h), 64 queries (16/wave). 32-key tiles.
// Q/K frags straight from global (K-major == MFMA A/B frag layout).
// V staged transposed in LDS; P goes C-layout -> A-layout through per-wave LDS.
// Q was pre-scaled by 1/sqrt(D).
// ---------------------------------------------------------------------------
__global__ __launch_bounds__(256)
void flash(const bf16* __restrict__ Q, const bf16* __restrict__ K,
           const bf16* __restrict__ V, bf16* __restrict__ Y) {
    __shared__ __align__(16) bf16 vsh[64][48];        // [d][key], pad 32->48
    __shared__ __align__(16) bf16 psh[4][16][32];     // per-wave P tile
    const int tid  = threadIdx.x;
    const int lane = tid & 63;
    const int wave = tid >> 6;
    const int quad = lane >> 4;
    const int l16  = lane & 15;
    const int bh   = blockIdx.y;
    const int qb   = blockIdx.x;
    const size_t base = (size_t)bh * T_SEQ * DH;

    // Q fragment: m = l16 -> query qb*64 + wave*16 + l16 ; k = quad*8 (+32)
    const bf16* qp = Q + base + (size_t)(qb * 64 + wave * 16 + l16) * DH + quad * 8;
    const bf16x8 aq0 = *(const bf16x8*)qp;
    const bf16x8 aq1 = *(const bf16x8*)(qp + 32);

    float mi[4], li[4];
    f32x4 o[4];
    const f32x4 zero4 = {0.f, 0.f, 0.f, 0.f};
#pragma unroll
    for (int r = 0; r < 4; r++) { mi[r] = -INFINITY; li[r] = 0.f; }
#pragma unroll
    for (int g = 0; g < 4; g++) o[g] = zero4;

    const int vkey = tid >> 3;          // 0..31
    const int vd0  = (tid & 7) * 8;     // 0..56

    for (int kt = 0; kt < T_SEQ; kt += 32) {
        // stage V tile (32 keys x 64 d) transposed into LDS
        bf16x8 vv = *(const bf16x8*)(V + base + (size_t)(kt + vkey) * DH + vd0);
        __syncthreads();   // everyone done reading vsh from previous tile
#pragma unroll
        for (int j = 0; j < 8; j++) vsh[vd0 + j][vkey] = vv[j];
        __syncthreads();   // vsh ready

        // V fragments into registers now (so next-iter staging can't race)
        bf16x8 vb[4];
#pragma unroll
        for (int g = 0; g < 4; g++)
            vb[g] = *(const bf16x8*)&vsh[g * 16 + l16][quad * 8];

        // S = Q K^T for 2 groups of 16 keys
        const bf16* kp = K + base + (size_t)kt * DH;
        f32x4 s0 = zero4, s1 = zero4;
        {
            const bf16* k0 = kp + (size_t)l16 * DH + quad * 8;
            s0 = MFMA16(aq0, *(const bf16x8*)k0, s0);
            s0 = MFMA16(aq1, *(const bf16x8*)(k0 + 32), s0);
            const bf16* k1 = kp + (size_t)(16 + l16) * DH + quad * 8;
            s1 = MFMA16(aq0, *(const bf16x8*)k1, s1);
            s1 = MFMA16(aq1, *(const bf16x8*)(k1 + 32), s1);
        }

        // online softmax (rows = quad*4+r; cols live across the 16-lane group)
        float p0[4], p1[4], alpha[4];
#pragma unroll
        for (int r = 0; r < 4; r++) {
            float tmax = fmaxf(s0[r], s1[r]);
#pragma unroll
            for (int msk = 1; msk < 16; msk <<= 1)
                tmax = fmaxf(tmax, __shfl_xor(tmax, msk));
            const float mnew = fmaxf(mi[r], tmax);
            alpha[r] = __expf(mi[r] - mnew);
            mi[r] = mnew;
            p0[r] = __expf(s0[r] - mnew);
            p1[r] = __expf(s1[r] - mnew);
            float rs = p0[r] + p1[r];
#pragma unroll
            for (int msk = 1; msk < 16; msk <<= 1)
                rs += __shfl_xor(rs, msk);
            li[r] = li[r] * alpha[r] + rs;
        }
#pragma unroll
        for (int g = 0; g < 4; g++) {
            o[g][0] *= alpha[0]; o[g][1] *= alpha[1];
            o[g][2] *= alpha[2]; o[g][3] *= alpha[3];
        }

        // P: C-layout -> A-layout through per-wave LDS (wave-private, in-order)
#pragma unroll
        for (int r = 0; r < 4; r++) {
            psh[wave][quad * 4 + r][l16]      = (bf16)p0[r];
            psh[wave][quad * 4 + r][16 + l16] = (bf16)p1[r];
        }
        const bf16x8 aP = *(const bf16x8*)&psh[wave][l16][quad * 8];
#pragma unroll
        for (int g = 0; g < 4; g++) o[g] = MFMA16(aP, vb[g], o[g]);
    }

    // epilogue: Y layout (B,T,C) = (b, t, h*64+d)
    const int b = bh >> 4, h = bh & 15;
#pragma unroll
    for (int r = 0; r < 4; r++) {
        const float inv = 1.0f / li[r];
        const int t = qb * 64 + wave * 16 + quad * 4 + r;
        const size_t row = ((size_t)b * T_SEQ + t) * CDIM + h * DH;
#pragma unroll
        for (int g = 0; g < 4; g++)
            Y[row + g * 16 + l16] = (bf16)(o[g][r] * inv);
    }
}

// ---------------------------------------------------------------------------
extern "C" void kernel_launch(void* const* d_in, const int* in_sizes, int n_in,
                              void* d_out, int out_size, void* d_ws, size_t ws_size,
                              hipStream_t stream) {
    const float* x      = (const float*)d_in[0];   // (4,2048,1024) fp32
    const float* w_attn = (const float*)d_in[1];   // (3072,1024) fp32
    const float* w_proj = (const float*)d_in[2];   // (1024,1024) fp32
    float* out = (float*)d_out;                    // (4,2048,1024) fp32

    bf16* ws = (bf16*)d_ws;
    const size_t SZ = (size_t)4 * NH * T_SEQ * DH;   // 8388608 elems
    bf16* Xb  = ws;                                  // 8388608
    bf16* Wab = Xb + SZ;                             // 3145728
    bf16* Wpb = Wab + 3145728;                       // 1048576
    bf16* Qb  = Wpb + 1048576;
    bf16* Kb  = Qb + SZ;
    bf16* Vb  = Kb + SZ;
    bf16* Yb  = Vb + SZ;

    // fp32 -> bf16 input conversion
    cvt_f32_bf16<<<4096, 256, 0, stream>>>(x, Xb, 1048576);
    cvt_f32_bf16<<<1536, 256, 0, stream>>>(w_attn, Wab, 393216);
    cvt_f32_bf16<<<512, 256, 0, stream>>>(w_proj, Wpb, 131072);

    // qkv = x @ w_attn^T (+RoPE, +1/sqrt(D) on Q) -> Q,K,V (B,H,T,D)
    gemm_qkv<<<dim3(48, 128), 256, 0, stream>>>(Xb, Wab, Qb, Kb, Vb);
    // flash attention -> Y (B,T,C)
    flash<<<dim3(T_SEQ / 64, 4 * NH), 256, 0, stream>>>(Qb, Kb, Vb, Yb);
    // out = Y @ w_proj^T  (fp32 out)
    gemm_proj<<<dim3(16, 128), 256, 0, stream>>>(Yb, Wpb, out);
}